// Round 1
// baseline (439.377 us; speedup 1.0000x reference)
//
#include <hip/hip_runtime.h>

// Problem constants (from reference):
// B=256, D=8192, S=8, W=4, NSLOTS=2048, STATE_LEN=3
#define BB 256
#define DD 8192
#define SS 8
#define WW 4
#define NSLOTS 2048
#define STATE_LEN 3

// ---------------------------------------------------------------------------
// Kernel 1: bulk copy conv_states -> new_conv_states output region.
// 50,331,648 floats = 12,582,912 float4 — exactly covered by grid.
// ---------------------------------------------------------------------------
__global__ void copy_states_kernel(const float4* __restrict__ src,
                                   float4* __restrict__ dst, int n4) {
    int i = blockIdx.x * blockDim.x + threadIdx.x;
    int stride = gridDim.x * blockDim.x;
    for (; i < n4; i += stride) {
        dst[i] = src[i];
    }
}

// ---------------------------------------------------------------------------
// Kernel 2: per-(b,d) conv update.
//   out[b,d,s] = sum_k cat[s+k]*w[d,k] (+ x[b,d,s] if residual)
//   cat = [st0, st1, st2, x0..x7]   (len 11)
//   new_state[idx,d,:] = x[b,d,5:8] if valid else st
// grid: B * (D/256) = 256*32 = 8192 blocks of 256 threads.
// blockIdx.x = b*32 + dchunk ; d = dchunk*256 + tid
// ---------------------------------------------------------------------------
__global__ __launch_bounds__(256)
void conv_update_kernel(const float* __restrict__ x,
                        const float* __restrict__ weight,
                        const float* __restrict__ conv_states,
                        const int* __restrict__ cache_indices,
                        const int* __restrict__ residual_p,
                        const int* __restrict__ pad_p,
                        float* __restrict__ out,
                        float* __restrict__ out_ns) {
    const int b = blockIdx.x >> 5;                       // /32
    const int d = ((blockIdx.x & 31) << 8) | threadIdx.x;

    const int idx_raw = cache_indices[b];                // wave-uniform
    const int pad = pad_p[0];
    const bool valid = (idx_raw != pad);
    const int idx = valid ? idx_raw : 0;
    const int res = residual_p[0];

    // x row: 8 floats, 32B aligned
    const float4* xr = (const float4*)(x + ((size_t)b * DD + d) * SS);
    float4 x0 = xr[0];
    float4 x1 = xr[1];

    // weight row: 4 floats
    float4 wv = ((const float4*)weight)[d];

    // state row: 3 floats (contiguous across d within the block)
    const float* st = conv_states + ((size_t)idx * DD + d) * STATE_LEN;
    float s0 = st[0], s1 = st[1], s2 = st[2];

    float cat[11] = {s0, s1, s2,
                     x0.x, x0.y, x0.z, x0.w,
                     x1.x, x1.y, x1.z, x1.w};
    float o[8];
#pragma unroll
    for (int s = 0; s < SS; ++s) {
        o[s] = cat[s] * wv.x + cat[s + 1] * wv.y +
               cat[s + 2] * wv.z + cat[s + 3] * wv.w;
    }
    if (res) {
        o[0] += x0.x; o[1] += x0.y; o[2] += x0.z; o[3] += x0.w;
        o[4] += x1.x; o[5] += x1.y; o[6] += x1.z; o[7] += x1.w;
    }

    float4* orow = (float4*)(out + ((size_t)b * DD + d) * SS);
    orow[0] = make_float4(o[0], o[1], o[2], o[3]);
    orow[1] = make_float4(o[4], o[5], o[6], o[7]);

    // new state: x[5],x[6],x[7] = x1.y, x1.z, x1.w (valid), else keep st.
    // Invalid lanes write st back to slot 0 — identical to the copied data,
    // matching reference semantics (benign duplicate write).
    float* ns = out_ns + ((size_t)idx * DD + d) * STATE_LEN;
    ns[0] = valid ? x1.y : s0;
    ns[1] = valid ? x1.z : s1;
    ns[2] = valid ? x1.w : s2;
}

extern "C" void kernel_launch(void* const* d_in, const int* in_sizes, int n_in,
                              void* d_out, int out_size, void* d_ws, size_t ws_size,
                              hipStream_t stream) {
    const float* x           = (const float*)d_in[0];
    const float* weight      = (const float*)d_in[1];
    const float* conv_states = (const float*)d_in[2];
    const int*   cache_idx   = (const int*)d_in[3];
    const int*   residual_p  = (const int*)d_in[4];
    const int*   pad_p       = (const int*)d_in[5];

    float* out    = (float*)d_out;                         // B*D*S floats
    float* out_ns = out + (size_t)BB * DD * SS;            // NSLOTS*D*STATE_LEN floats

    // Kernel 1: copy states (12,582,912 float4)
    const int n4 = NSLOTS * DD * STATE_LEN / 4;
    const int cpThreads = 256;
    const int cpBlocks = n4 / cpThreads;                   // 49152, exact
    copy_states_kernel<<<cpBlocks, cpThreads, 0, stream>>>(
        (const float4*)conv_states, (float4*)out_ns, n4);

    // Kernel 2: conv + scatter state update
    const int blocks = BB * (DD / 256);                    // 8192
    conv_update_kernel<<<blocks, 256, 0, stream>>>(
        x, weight, conv_states, cache_idx, residual_p, pad_p, out, out_ns);
}

// Round 2
// 437.200 us; speedup vs baseline: 1.0050x; 1.0050x over previous
//
#include <hip/hip_runtime.h>

// Problem constants (from reference):
// B=256, D=8192, S=8, W=4, NSLOTS=2048, STATE_LEN=3
#define BB 256
#define DD 8192
#define SS 8
#define NSLOTS 2048
#define STATE_LEN 3

// ---------------------------------------------------------------------------
// Fused kernel, gridded over (slot, d-chunk): 2048*32 = 65536 blocks x 256.
//   block -> slot n = blockIdx.x>>5, dchunk = blockIdx.x&31
// Each block first resolves whether slot n is updated by some batch b:
//   thread t holds cache_indices[t]; match -> shared 'found' = t.
//   (cache_indices is 1 KB; L1/L2-resident across all blocks.)
// Unmapped slot: block bulk-copies its 3 KB state chunk via float4 (192 lanes).
// Mapped slot: per-d conv update:
//   cat = [st0,st1,st2, x0..x7]; out[s] = sum_k cat[s+k]*w[k] (+x[s] if res)
//   new_state = x[5:8]
// Traffic: 192R(states) + 64R(x) + 64W(out) + 192W(new_states) ~= 512 MiB.
// ---------------------------------------------------------------------------
__global__ __launch_bounds__(256)
void fused_conv_state_kernel(const float* __restrict__ x,
                             const float* __restrict__ weight,
                             const float* __restrict__ conv_states,
                             const int* __restrict__ cache_indices,
                             const int* __restrict__ residual_p,
                             const int* __restrict__ pad_p,
                             float* __restrict__ out,
                             float* __restrict__ out_ns) {
    const int n = blockIdx.x >> 5;          // slot
    const int dchunk = blockIdx.x & 31;
    const int tid = threadIdx.x;

    // --- resolve slot -> batch (block-uniform result) ---
    __shared__ int found;
    if (tid == 0) found = -1;
    __syncthreads();
    {
        const int ci = cache_indices[tid];   // thread t <-> batch t (BB==256)
        const int pad = pad_p[0];
        if (ci == n && ci != pad) found = tid;   // permutation: at most one match
    }
    __syncthreads();
    const int b = found;

    if (b < 0) {
        // Pure copy of this block's 3 KB state chunk: 768 floats = 192 float4.
        const size_t base4 =
            (((size_t)n * DD + (size_t)dchunk * 256) * STATE_LEN) >> 2;
        if (tid < 192) {
            ((float4*)out_ns)[base4 + tid] =
                ((const float4*)conv_states)[base4 + tid];
        }
        return;
    }

    // --- updated slot: conv output + new state ---
    const int d = (dchunk << 8) | tid;

    const size_t sbase = ((size_t)n * DD + d) * STATE_LEN;
    const float s0 = conv_states[sbase];
    const float s1 = conv_states[sbase + 1];
    const float s2 = conv_states[sbase + 2];

    const float4* xr = (const float4*)(x + ((size_t)b * DD + d) * SS);
    const float4 x0 = xr[0];
    const float4 x1 = xr[1];
    const float4 wv = ((const float4*)weight)[d];

    const float cat[11] = {s0, s1, s2,
                           x0.x, x0.y, x0.z, x0.w,
                           x1.x, x1.y, x1.z, x1.w};
    float o[8];
#pragma unroll
    for (int s = 0; s < SS; ++s) {
        o[s] = cat[s] * wv.x + cat[s + 1] * wv.y +
               cat[s + 2] * wv.z + cat[s + 3] * wv.w;
    }
    if (residual_p[0]) {
        o[0] += x0.x; o[1] += x0.y; o[2] += x0.z; o[3] += x0.w;
        o[4] += x1.x; o[5] += x1.y; o[6] += x1.z; o[7] += x1.w;
    }

    float4* orow = (float4*)(out + ((size_t)b * DD + d) * SS);
    orow[0] = make_float4(o[0], o[1], o[2], o[3]);
    orow[1] = make_float4(o[4], o[5], o[6], o[7]);

    // new state = x[..., 5:8]
    out_ns[sbase]     = x1.y;
    out_ns[sbase + 1] = x1.z;
    out_ns[sbase + 2] = x1.w;
}

extern "C" void kernel_launch(void* const* d_in, const int* in_sizes, int n_in,
                              void* d_out, int out_size, void* d_ws, size_t ws_size,
                              hipStream_t stream) {
    const float* x           = (const float*)d_in[0];
    const float* weight      = (const float*)d_in[1];
    const float* conv_states = (const float*)d_in[2];
    const int*   cache_idx   = (const int*)d_in[3];
    const int*   residual_p  = (const int*)d_in[4];
    const int*   pad_p       = (const int*)d_in[5];

    float* out    = (float*)d_out;                 // B*D*S floats
    float* out_ns = out + (size_t)BB * DD * SS;    // NSLOTS*D*STATE_LEN floats

    const int blocks = NSLOTS * (DD / 256);        // 65536
    fused_conv_state_kernel<<<blocks, 256, 0, stream>>>(
        x, weight, conv_states, cache_idx, residual_p, pad_p, out, out_ns);
}